// Round 1
// baseline (894.066 us; speedup 1.0000x reference)
//
#include <hip/hip_runtime.h>

typedef short bf16x8 __attribute__((ext_vector_type(8)));
typedef float f32x4 __attribute__((ext_vector_type(4)));

#define XPAD 200
#define QPAD 40
#define VPAD 72
#define PPAD 72
#define APAD 40

__device__ __forceinline__ short f2bf(float f) {
  unsigned x = __float_as_uint(f);
  x = (x + 0x7FFFu + ((x >> 16) & 1u)) >> 16;
  return (short)x;
}

// convert qkv_w (576*192) and proj_w (192*192) fp32 -> bf16 into workspace
__global__ void cvt_w(const float* __restrict__ qkv_w,
                      const float* __restrict__ proj_w,
                      short* __restrict__ wbf) {
  int idx = blockIdx.x * 256 + threadIdx.x;
  if (idx < 110592) wbf[idx] = f2bf(qkv_w[idx]);
  else if (idx < 147456) wbf[idx] = f2bf(proj_w[idx - 110592]);
}

// one block per 8x8 window; 512 threads = 8 waves
__global__ __launch_bounds__(512, 4) void swin_fused(
    const float* __restrict__ x,
    const float* __restrict__ qkv_b,
    const float* __restrict__ proj_b,
    const float* __restrict__ bias,
    const short* __restrict__ wbf,
    float* __restrict__ out) {
  __shared__ short lds_x[64 * XPAD];   // x window, bf16, [t][c] pad 200
  __shared__ short q1[64 * QPAD];      // head-current q, [t][d] pad 40 (scaled)
  __shared__ short k1[64 * QPAD];      // head-current k, [t][d] pad 40
  __shared__ short v1[32 * VPAD];      // head-current v, [d][t] pad 72
  __shared__ short p_s[4 * 16 * PPAD]; // per-attn-wave P transpose scratch
  __shared__ short att1[64 * APAD];    // head-current attn output [t][d] pad 40
  // total 27392 shorts = 54784 B  (< 64 KB -> 2 blocks/CU)

  const short* qw = wbf;           // [576][192] bf16
  const short* pw = wbf + 110592;  // [192][192] bf16

  const int wid = blockIdx.x;
  const int b = wid >> 10;
  const int rem = wid & 1023;
  const int wh = rem >> 5;
  const int ww = rem & 31;

  const int tid = threadIdx.x;
  const int w = tid >> 6;     // wave id 0..7
  const int lane = tid & 63;
  const int quad = lane >> 4; // 0..3
  const int lm = lane & 15;   // 0..15

  const size_t base = ((size_t)b * 65536 + (size_t)(wh * 8) * 256 + (size_t)(ww * 8)) * 192;
  const float* xwin = x + base;

  // ---- stage x window -> LDS bf16 ----
  // window = 8 chunks (rows) of 1536 contiguous floats each
  #pragma unroll
  for (int it = 0; it < 6; ++it) {
    int idx4 = tid + it * 512;          // [0,3072) float4 index
    int chunk = idx4 / 384;             // window row i (0..7)
    int off = idx4 - chunk * 384;       // float4 within chunk
    float4 f = *(const float4*)(xwin + (size_t)chunk * 49152 + (size_t)off * 4);
    int t = chunk * 8 + off / 48;       // token
    int c = (off % 48) * 4;             // channel
    short4 s;
    s.x = f2bf(f.x); s.y = f2bf(f.y); s.z = f2bf(f.z); s.w = f2bf(f.w);
    *(short4*)&lds_x[t * XPAD + c] = s;
  }
  __syncthreads();

  const int mt = w >> 1;  // 16-token tile owned in QKV/proj phases

  f32x4 pacc[6];
  #pragma unroll
  for (int i = 0; i < 6; ++i) pacc[i] = (f32x4){0.f, 0.f, 0.f, 0.f};

  for (int h = 0; h < 6; ++h) {
    // ---------- QKV for head h: M=64, N=96 (q32|k32|v32), K=192 ----------
    {
      bf16x8 af[6];
      #pragma unroll
      for (int ks = 0; ks < 6; ++ks)
        af[ks] = *(const bf16x8*)&lds_x[(mt * 16 + lm) * XPAD + ks * 32 + quad * 8];
      #pragma unroll
      for (int ntl = 0; ntl < 3; ++ntl) {
        int nt = (w & 1) * 3 + ntl;     // 0..5
        int sec = nt >> 1;              // 0=q 1=k 2=v
        int dh = nt & 1;                // which 16-dim half
        int n0 = sec * 192 + h * 32 + dh * 16 + lm;  // qkv_w row
        f32x4 acc = {0.f, 0.f, 0.f, 0.f};
        #pragma unroll
        for (int ks = 0; ks < 6; ++ks) {
          bf16x8 bf = *(const bf16x8*)&qw[n0 * 192 + ks * 32 + quad * 8];
          acc = __builtin_amdgcn_mfma_f32_16x16x32_bf16(af[ks], bf, acc, 0, 0, 0);
        }
        float bn = qkv_b[n0];
        int d = dh * 16 + lm;
        #pragma unroll
        for (int r = 0; r < 4; ++r) {
          int t = mt * 16 + quad * 4 + r;
          float val = acc[r] + bn;
          if (sec == 0)      q1[t * QPAD + d] = f2bf(val * 0.17677669529663689f);
          else if (sec == 1) k1[t * QPAD + d] = f2bf(val);
          else               v1[d * VPAD + t] = f2bf(val);
        }
      }
    }
    __syncthreads();

    // ---------- attention for head h (waves 0..3, one m-tile each) ----------
    if (w < 4) {
      const int amt = w;
      bf16x8 aq = *(const bf16x8*)&q1[(amt * 16 + lm) * QPAD + quad * 8];
      f32x4 lg[4];
      #pragma unroll
      for (int nt = 0; nt < 4; ++nt) {
        bf16x8 bk = *(const bf16x8*)&k1[(nt * 16 + lm) * QPAD + quad * 8];
        f32x4 z = {0.f, 0.f, 0.f, 0.f};
        lg[nt] = __builtin_amdgcn_mfma_f32_16x16x32_bf16(aq, bk, z, 0, 0, 0);
      }
      const float* bh = bias + h * 4096;
      #pragma unroll
      for (int nt = 0; nt < 4; ++nt) {
        #pragma unroll
        for (int r = 0; r < 4; ++r)
          lg[nt][r] += bh[(amt * 16 + quad * 4 + r) * 64 + nt * 16 + lm];
      }
      #pragma unroll
      for (int r = 0; r < 4; ++r) {
        float mx = fmaxf(fmaxf(lg[0][r], lg[1][r]), fmaxf(lg[2][r], lg[3][r]));
        mx = fmaxf(mx, __shfl_xor(mx, 1));
        mx = fmaxf(mx, __shfl_xor(mx, 2));
        mx = fmaxf(mx, __shfl_xor(mx, 4));
        mx = fmaxf(mx, __shfl_xor(mx, 8));
        float e0 = __expf(lg[0][r] - mx);
        float e1 = __expf(lg[1][r] - mx);
        float e2 = __expf(lg[2][r] - mx);
        float e3 = __expf(lg[3][r] - mx);
        float s = e0 + e1 + e2 + e3;
        s += __shfl_xor(s, 1);
        s += __shfl_xor(s, 2);
        s += __shfl_xor(s, 4);
        s += __shfl_xor(s, 8);
        float inv = 1.0f / s;
        short* pr = &p_s[(w * 16 + quad * 4 + r) * PPAD];
        pr[0 * 16 + lm] = f2bf(e0 * inv);
        pr[1 * 16 + lm] = f2bf(e1 * inv);
        pr[2 * 16 + lm] = f2bf(e2 * inv);
        pr[3 * 16 + lm] = f2bf(e3 * inv);
      }
      // same-wave LDS RAW: drain ds_writes before transposed re-read
      asm volatile("s_waitcnt lgkmcnt(0)" ::: "memory");
      f32x4 o0 = {0.f, 0.f, 0.f, 0.f}, o1 = {0.f, 0.f, 0.f, 0.f};
      #pragma unroll
      for (int ks = 0; ks < 2; ++ks) {
        bf16x8 ap  = *(const bf16x8*)&p_s[(w * 16 + lm) * PPAD + ks * 32 + quad * 8];
        bf16x8 bv0 = *(const bf16x8*)&v1[(0 * 16 + lm) * VPAD + ks * 32 + quad * 8];
        bf16x8 bv1 = *(const bf16x8*)&v1[(1 * 16 + lm) * VPAD + ks * 32 + quad * 8];
        o0 = __builtin_amdgcn_mfma_f32_16x16x32_bf16(ap, bv0, o0, 0, 0, 0);
        o1 = __builtin_amdgcn_mfma_f32_16x16x32_bf16(ap, bv1, o1, 0, 0, 0);
      }
      #pragma unroll
      for (int r = 0; r < 4; ++r) {
        int t = amt * 16 + quad * 4 + r;
        att1[t * APAD + lm]      = f2bf(o0[r]);
        att1[t * APAD + 16 + lm] = f2bf(o1[r]);
      }
    }
    __syncthreads();

    // ---------- proj partial: out += att1 @ proj_w[:, h*32:(h+1)*32].T ----------
    {
      bf16x8 aa = *(const bf16x8*)&att1[(mt * 16 + lm) * APAD + quad * 8];
      #pragma unroll
      for (int ntl = 0; ntl < 6; ++ntl) {
        int n0 = (w & 1) * 96 + ntl * 16 + lm;
        bf16x8 bp = *(const bf16x8*)&pw[n0 * 192 + h * 32 + quad * 8];
        pacc[ntl] = __builtin_amdgcn_mfma_f32_16x16x32_bf16(aa, bp, pacc[ntl], 0, 0, 0);
      }
    }
    __syncthreads();
  }

  // ---------- epilogue: bias + store fp32 ----------
  #pragma unroll
  for (int ntl = 0; ntl < 6; ++ntl) {
    int n0 = (w & 1) * 96 + ntl * 16 + lm;
    float pb = proj_b[n0];
    #pragma unroll
    for (int r = 0; r < 4; ++r) {
      int t = mt * 16 + quad * 4 + r;
      int ti = t >> 3, tj = t & 7;
      out[base + (size_t)(ti * 256 + tj) * 192 + n0] = pacc[ntl][r] + pb;
    }
  }
}

extern "C" void kernel_launch(void* const* d_in, const int* in_sizes, int n_in,
                              void* d_out, int out_size, void* d_ws, size_t ws_size,
                              hipStream_t stream) {
  const float* x      = (const float*)d_in[0];
  const float* qkv_w  = (const float*)d_in[1];
  const float* qkv_b  = (const float*)d_in[2];
  const float* proj_w = (const float*)d_in[3];
  const float* proj_b = (const float*)d_in[4];
  const float* bias   = (const float*)d_in[5];
  short* wbf = (short*)d_ws;  // 147456 shorts = 294912 B

  hipLaunchKernelGGL(cvt_w, dim3(576), dim3(256), 0, stream, qkv_w, proj_w, wbf);
  hipLaunchKernelGGL(swin_fused, dim3(4096), dim3(512), 0, stream,
                     x, qkv_b, proj_b, bias, wbf, (float*)d_out);
}

// Round 2
// 605.560 us; speedup vs baseline: 1.4764x; 1.4764x over previous
//
#include <hip/hip_runtime.h>

typedef short bf16x8 __attribute__((ext_vector_type(8)));
typedef float f32x4 __attribute__((ext_vector_type(4)));

#define QKV_FRAG_SH 110592
#define PROJ_FRAG_SH 36864
#define EBIAS_OFF_B 294912
#define SCALE 0.17677669529663689f
#define SMEM_BYTES 158720

__device__ __forceinline__ short f2bf(float f) {
  unsigned x = __float_as_uint(f);
  x = (x + 0x7FFFu + ((x >> 16) & 1u)) >> 16;
  return (short)x;
}

// Pre-transform: weights -> MFMA-fragment-contiguous bf16 layout (one wave frag
// load = 1 KB contiguous); q rows pre-scaled by 1/sqrt(hd); bias -> exp(bias).
__global__ void cvt_w(const float* __restrict__ qkv_w,
                      const float* __restrict__ proj_w,
                      const float* __restrict__ bias,
                      short* __restrict__ wfrag,
                      float* __restrict__ ebias) {
  int idx = blockIdx.x * 256 + threadIdx.x;
  if (idx < QKV_FRAG_SH) {
    int j = idx & 7, lane = (idx >> 3) & 63, t = idx >> 9;
    int nt = t / 6, ks = t - nt * 6;
    int n0 = nt * 16 + (lane & 15);
    float v = qkv_w[n0 * 192 + ks * 32 + (lane >> 4) * 8 + j];
    if (n0 < 192) v *= SCALE;
    wfrag[idx] = f2bf(v);
  } else if (idx < QKV_FRAG_SH + PROJ_FRAG_SH) {
    int i2 = idx - QKV_FRAG_SH;
    int j = i2 & 7, lane = (i2 >> 3) & 63, t = i2 >> 9;
    int nt = t / 6, ks = t - nt * 6;
    wfrag[idx] = f2bf(proj_w[(nt * 16 + (lane & 15)) * 192 + ks * 32 + (lane >> 4) * 8 + j]);
  } else {
    int i3 = idx - (QKV_FRAG_SH + PROJ_FRAG_SH);
    ebias[i3] = __expf(bias[i3]);
  }
}

// Persistent: grid=256 blocks (1/CU, full-LDS), each loops 16 windows.
// Per window: [prefetch next x to regs] QKV(all heads) | B1 | [write prefetch]
// attention(24 tasks) | B2 | proj.  2 barriers/window.
__global__ __launch_bounds__(512, 2) void swin_fused(
    const float* __restrict__ x,
    const float* __restrict__ qkv_b,
    const float* __restrict__ proj_b,
    const short* __restrict__ wfrag,
    const float* __restrict__ ebias,
    float* __restrict__ out) {
  extern __shared__ short smem[];
  short* buf = smem;              // 2 x [64][200]  x(bf16) then reused for att
  short* q_l = smem + 25600;      // [6][64][40]  (pre-scaled)
  short* k_l = smem + 40960;      // [6][64][40]
  short* v_l = smem + 56320;      // [6][32][72]  (v transposed: [d][t])
  short* p_s = smem + 70144;      // [8][16][72]  per-wave P scratch

  const short* wq = wfrag;
  const short* wp = wfrag + QKV_FRAG_SH;

  const int tid = threadIdx.x;
  const int w = tid >> 6, lane = tid & 63, quad = lane >> 4, lm = lane & 15;
  const int m = w & 3;

  // staging index precompute (6 float4 per thread, window = 8 chunks of 1536 floats)
  int goff[6], loff[6];
  #pragma unroll
  for (int i = 0; i < 6; ++i) {
    int idx4 = tid + i * 512;
    int chunk = idx4 / 384;
    int off = idx4 - chunk * 384;
    goff[i] = chunk * 49152 + off * 4;
    loff[i] = (chunk * 8 + off / 48) * 200 + (off % 48) * 4;
  }

  // prologue: stage window it=0
  size_t base;
  {
    int wid = blockIdx.x;
    int b = wid >> 10, rem = wid & 1023, wh = rem >> 5, ww = rem & 31;
    base = ((size_t)b * 65536 + (size_t)(wh * 8) * 256 + (size_t)(ww * 8)) * 192;
    const float* xp = x + base;
    #pragma unroll
    for (int i = 0; i < 6; ++i) {
      float4 f = *(const float4*)(xp + goff[i]);
      short4 s = { f2bf(f.x), f2bf(f.y), f2bf(f.z), f2bf(f.w) };
      *(short4*)&buf[loff[i]] = s;
    }
  }
  __syncthreads();

  float4 pf[6];
  size_t nbase = 0;
  #pragma unroll 1
  for (int it = 0; it < 16; ++it) {
    const int cur = (it & 1) * 12800;
    const int nxt = 12800 - cur;

    // prefetch next window into regs (lands during QKV phase)
    if (it < 15) {
      int wid = (it + 1) * 256 + blockIdx.x;
      int b = wid >> 10, rem = wid & 1023, wh = rem >> 5, ww = rem & 31;
      nbase = ((size_t)b * 65536 + (size_t)(wh * 8) * 256 + (size_t)(ww * 8)) * 192;
      const float* xp = x + nbase;
      #pragma unroll
      for (int i = 0; i < 6; ++i) pf[i] = *(const float4*)(xp + goff[i]);
    }

    // ---------------- QKV: M=64, N=576, K=192 ----------------
    // wave w: m-tile = w&3, n-tiles (w>>2)*18 .. +18 (4 waves sweep same n-tiles -> L1 reuse)
    {
      bf16x8 af[6];
      #pragma unroll
      for (int ks = 0; ks < 6; ++ks)
        af[ks] = *(const bf16x8*)&buf[cur + (m * 16 + lm) * 200 + ks * 32 + quad * 8];
      const int nt0 = (w >> 2) * 18;
      for (int ntl = 0; ntl < 18; ++ntl) {
        int nt = nt0 + ntl;
        f32x4 acc = {0.f, 0.f, 0.f, 0.f};
        #pragma unroll
        for (int ks = 0; ks < 6; ++ks) {
          bf16x8 bw = *(const bf16x8*)&wq[((nt * 6 + ks) * 64 + lane) * 8];
          acc = __builtin_amdgcn_mfma_f32_16x16x32_bf16(af[ks], bw, acc, 0, 0, 0);
        }
        float bn = qkv_b[nt * 16 + lm];
        if (nt < 12) {            // q (weights+bias pre-scaled)
          bn *= SCALE;
          int h = nt >> 1, dh = nt & 1;
          int rb = h * 64 + m * 16 + quad * 4;
          #pragma unroll
          for (int r = 0; r < 4; ++r)
            q_l[(rb + r) * 40 + dh * 16 + lm] = f2bf(acc[r] + bn);
        } else if (nt < 24) {     // k
          int h = (nt - 12) >> 1, dh = nt & 1;
          int rb = h * 64 + m * 16 + quad * 4;
          #pragma unroll
          for (int r = 0; r < 4; ++r)
            k_l[(rb + r) * 40 + dh * 16 + lm] = f2bf(acc[r] + bn);
        } else {                  // v transposed [d][t], 4 consecutive t -> short4
          int h = (nt - 24) >> 1, dh = nt & 1;
          short4 s4 = { f2bf(acc[0] + bn), f2bf(acc[1] + bn),
                        f2bf(acc[2] + bn), f2bf(acc[3] + bn) };
          *(short4*)&v_l[(h * 32 + dh * 16 + lm) * 72 + m * 16 + quad * 4] = s4;
        }
      }
    }
    __syncthreads();  // B1: q/k/v ready; x[cur] reads done

    // write prefetched x -> buf[nxt] (consumed after next-iteration's start; fenced by B2)
    if (it < 15) {
      #pragma unroll
      for (int i = 0; i < 6; ++i) {
        short4 s = { f2bf(pf[i].x), f2bf(pf[i].y), f2bf(pf[i].z), f2bf(pf[i].w) };
        *(short4*)&buf[nxt + loff[i]] = s;
      }
    }

    // ---------------- attention: 24 (h, mt) tasks over 8 waves ----------------
    // no-max softmax, deferred normalization: o = (P_unnorm V) / rowsum
    {
      const int pb = w * 1152;
      #pragma unroll 1
      for (int i = 0; i < 3; ++i) {
        int tk = w + i * 8;
        int h = tk >> 2, mt = tk & 3;
        float eb[4][4];
        const float* ebp = ebias + h * 4096 + (mt * 16 + quad * 4) * 64 + lm;
        #pragma unroll
        for (int nt = 0; nt < 4; ++nt)
          #pragma unroll
          for (int r = 0; r < 4; ++r)
            eb[nt][r] = ebp[r * 64 + nt * 16];
        bf16x8 aq = *(const bf16x8*)&q_l[(h * 64 + mt * 16 + lm) * 40 + quad * 8];
        f32x4 lg[4];
        #pragma unroll
        for (int nt = 0; nt < 4; ++nt) {
          bf16x8 bk = *(const bf16x8*)&k_l[(h * 64 + nt * 16 + lm) * 40 + quad * 8];
          f32x4 z = {0.f, 0.f, 0.f, 0.f};
          lg[nt] = __builtin_amdgcn_mfma_f32_16x16x32_bf16(aq, bk, z, 0, 0, 0);
        }
        float s[4] = {0.f, 0.f, 0.f, 0.f};
        #pragma unroll
        for (int r = 0; r < 4; ++r) {
          #pragma unroll
          for (int nt = 0; nt < 4; ++nt) {
            float e = __expf(lg[nt][r]) * eb[nt][r];
            s[r] += e;
            p_s[pb + (quad * 4 + r) * 72 + nt * 16 + lm] = f2bf(e);
          }
        }
        #pragma unroll
        for (int r = 0; r < 4; ++r) {   // overlaps with p_s write drain
          s[r] += __shfl_xor(s[r], 1);
          s[r] += __shfl_xor(s[r], 2);
          s[r] += __shfl_xor(s[r], 4);
          s[r] += __shfl_xor(s[r], 8);
        }
        asm volatile("s_waitcnt lgkmcnt(0)" ::: "memory");  // same-wave P RAW
        f32x4 o0 = {0.f,0.f,0.f,0.f}, o1 = {0.f,0.f,0.f,0.f};
        #pragma unroll
        for (int ks = 0; ks < 2; ++ks) {
          bf16x8 ap  = *(const bf16x8*)&p_s[pb + lm * 72 + ks * 32 + quad * 8];
          bf16x8 bv0 = *(const bf16x8*)&v_l[(h * 32 + lm) * 72 + ks * 32 + quad * 8];
          bf16x8 bv1 = *(const bf16x8*)&v_l[(h * 32 + 16 + lm) * 72 + ks * 32 + quad * 8];
          o0 = __builtin_amdgcn_mfma_f32_16x16x32_bf16(ap, bv0, o0, 0, 0, 0);
          o1 = __builtin_amdgcn_mfma_f32_16x16x32_bf16(ap, bv1, o1, 0, 0, 0);
        }
        #pragma unroll
        for (int r = 0; r < 4; ++r) {
          float ir = 1.0f / s[r];
          int rowo = cur + (mt * 16 + quad * 4 + r) * 200 + h * 32;
          buf[rowo + lm]      = f2bf(o0[r] * ir);
          buf[rowo + 16 + lm] = f2bf(o1[r] * ir);
        }
      }
    }
    __syncthreads();  // B2: att ready in buf[cur]; prefetch writes to buf[nxt] done

    // ---------------- proj: M=64, N=192, K=192 ----------------
    // (no trailing barrier needed: next QKV only writes q/k/v + reads buf[nxt])
    {
      bf16x8 af2[6];
      #pragma unroll
      for (int ks = 0; ks < 6; ++ks)
        af2[ks] = *(const bf16x8*)&buf[cur + (m * 16 + lm) * 200 + ks * 32 + quad * 8];
      const int nt0 = (w >> 2) * 6;
      #pragma unroll 1
      for (int ntl = 0; ntl < 6; ++ntl) {
        int nt = nt0 + ntl;
        f32x4 acc = {0.f, 0.f, 0.f, 0.f};
        #pragma unroll
        for (int ks = 0; ks < 6; ++ks) {
          bf16x8 bw = *(const bf16x8*)&wp[((nt * 6 + ks) * 64 + lane) * 8];
          acc = __builtin_amdgcn_mfma_f32_16x16x32_bf16(af2[ks], bw, acc, 0, 0, 0);
        }
        float pbv = proj_b[nt * 16 + lm];
        #pragma unroll
        for (int r = 0; r < 4; ++r) {
          int t = m * 16 + quad * 4 + r;
          out[base + (size_t)((t >> 3) * 256 + (t & 7)) * 192 + nt * 16 + lm] = acc[r] + pbv;
        }
      }
    }
    base = nbase;
  }
}

extern "C" void kernel_launch(void* const* d_in, const int* in_sizes, int n_in,
                              void* d_out, int out_size, void* d_ws, size_t ws_size,
                              hipStream_t stream) {
  const float* x      = (const float*)d_in[0];
  const float* qkv_w  = (const float*)d_in[1];
  const float* qkv_b  = (const float*)d_in[2];
  const float* proj_w = (const float*)d_in[3];
  const float* proj_b = (const float*)d_in[4];
  const float* bias   = (const float*)d_in[5];
  short* wfrag = (short*)d_ws;                           // 294912 B
  float* ebias = (float*)((char*)d_ws + EBIAS_OFF_B);    // 98304 B

  hipFuncSetAttribute((const void*)swin_fused,
                      hipFuncAttributeMaxDynamicSharedMemorySize, SMEM_BYTES);

  hipLaunchKernelGGL(cvt_w, dim3(672), dim3(256), 0, stream,
                     qkv_w, proj_w, bias, wfrag, ebias);
  hipLaunchKernelGGL(swin_fused, dim3(256), dim3(512), SMEM_BYTES, stream,
                     x, qkv_b, proj_b, wfrag, ebias, (float*)d_out);
}